// Round 15
// baseline (287.284 us; speedup 1.0000x reference)
//
#include <hip/hip_runtime.h>
#include <math.h>

// MeanShift: x (2,3,96,96) fp32, 5 iters of all-pairs Gaussian-weighted mean.
// R14 structure (best 237us: grid 1728 all-resident, SoA fold-in, atomic
// exchange) with v_exp_f32 (16 cyc/wave64, 66% of the issue port) replaced by
// a FULLY-VECTOR bit-trick exp2 (9 insts / 18 cyc per 2 weights):
//   t = u + 217 in [0.6, 217.4]   (u = 2p.y-|p|^2-|y|^2 >= -3s^2 = -216.4)
//   f = t - floor(t);  g = f(1-f)(A + B f)   (cubic: 2^f-1-f fit, ~3e-4 rel)
//   V = 2^23 * t + g*2^23;  w = bit_cast<float>((int)V) = 2^(u+90)*(1+-3e-4)
// Uniform 2^90 cancels in num/den (den<=2^104, num<=2^108, pack f~2^-106.6:
// all normal f32). V<=1.83e9<INT_MAX: no cvt saturation (R5/R6's NaN bug).
// NO element accesses in the weight path -- R7's fast-exp scalarized because
// of .x/.y insertion; elementwise_floor/convertvector/bit_cast lower without
// repacking. If this scalarizes anyway (busy unchanged ~26.5us/iter): revert
// to R14 + declare roofline (closed model: 390cyc/16 pairs, 65% port util).
//
// Validated issue model: old 390 cyc/superiter (128 pk + 256 exp); new 272.
// launch_bounds(256,4) only -- min-waves=7 caused acc spills (R12).

typedef float v2f __attribute__((ext_vector_type(2)));
typedef int   v2i __attribute__((ext_vector_type(2)));

#define NPTS   9216            // 96*96
#define NB     2
#define TOT    (NB * NPTS)     // 18432
#define MSPLIT 24              // m-slices per n-tile
#define SLICE  (NPTS / MSPLIT) // 384 m per block
#define WSLICE (SLICE / 4)     // 96 m per wave (= 12 x 8)
#define NPB    256             // n per block (4 per thread)
#define NTILES (NPTS / NPB)    // 36
#define GRIDSZ (NB * NTILES * MSPLIT)  // 1728 = 6.75/CU, all-resident
#define LOG2E  1.44269504088896340736f
#define BIASF  217.0f          // > 3*s^2 = 216.4 -> t always positive
#define T23F   8388608.0f      // 2^23
#define A2F    -2574068.9f     // (ln2-1) * 2^23
#define B2F    -666404.0f      // (-(2ln2-1)-(ln2-1)) * 2^23

__device__ __forceinline__ v2f splat2(float v) { return (v2f){v, v}; }

// Weight for 2 pairs: w = 2^(t-127), t in (0, 218). All vector ops.
__device__ __forceinline__ v2f fast_exp2(v2f t, v2f T23, v2f A2, v2f B2) {
    v2f F = __builtin_elementwise_floor(t);     // 2x v_floor_f32
    v2f f = t - F;                              // v_pk_add (neg)
    v2f h = __builtin_elementwise_fma(-f, f, f);    // f(1-f)
    v2f c = __builtin_elementwise_fma(f, B2, A2);   // (A + B f), pre-scaled 2^23
    v2f g = h * c;
    v2f V = __builtin_elementwise_fma(t, T23, g);
    v2i I = __builtin_convertvector(V, v2i);    // 2x v_cvt_i32_f32
    return __builtin_bit_cast(v2f, I);          // free reinterpret
}

// soa[b] = 4 arrays of NPTS floats: X2(=2px), Y2, Z2, W(=-|p|^2), scaled.
// acc[t][gid] = float4(num0,num1,num2,den), t=0..4, pre-zeroed, atomic-combined.

__global__ __launch_bounds__(256, 4) void ms_iter(const float* __restrict__ x,
                                                  float* __restrict__ soa,
                                                  const float4* __restrict__ accIn,
                                                  float4* __restrict__ accOut,
                                                  float s, int first) {
    __shared__ float4 smem[1024];               // 16 KB
    float* const xs = (float*)smem;             // [SLICE] 2*px
    float* const ys = xs + SLICE;               // 2*py
    float* const zs = ys + SLICE;               // 2*pz
    float* const ws = zs + SLICE;               // -|p|^2  (ends at 1536 floats)
    float4* const ypar = smem + 384;            // [NPB] after 1536 floats
    float4* const red  = smem;                  // [4][NPB] overlay (post-loop)

    const int tid  = threadIdx.x;
    const int lane = tid & 63;
    const int wv   = tid >> 6;
    const int k    = blockIdx.x % MSPLIT;
    const int tile = blockIdx.x / MSPLIT;
    const int b    = tile / NTILES;
    const int nt   = tile - b * NTILES;
    const int nbase = nt * NPB;
    const float* xb = x + b * 3 * NPTS;
    float* sb = soa + (size_t)b * 4 * NPTS;
    const int mbeg = k * SLICE;

    if (first) {
        // Compute scaled slice from x; nt==0 block also publishes it to SoA.
        for (int i = tid; i < SLICE; i += 256) {
            int g = mbeg + i;
            float px = xb[g] * s;
            float py = xb[NPTS + g] * s;
            float pz = xb[2 * NPTS + g] * s;
            float X2 = 2.f * px, Y2 = 2.f * py, Z2 = 2.f * pz;
            float W = -fmaf(px, px, fmaf(py, py, pz * pz));
            xs[i] = X2; ys[i] = Y2; zs[i] = Z2; ws[i] = W;
            if (nt == 0) {
                sb[g]            = X2;
                sb[NPTS + g]     = Y2;
                sb[2 * NPTS + g] = Z2;
                sb[3 * NPTS + g] = W;
            }
        }
    } else {
        // Staging: pure coalesced copy from precomputed SoA.
        for (int i = tid; i < SLICE; i += 256) {
            int g = mbeg + i;
            xs[i] = sb[g];
            ys[i] = sb[NPTS + g];
            zs[i] = sb[2 * NPTS + g];
            ws[i] = sb[3 * NPTS + g];
        }
    }
    // y for this iteration (scaled space). PLAIN y (2x lives in LDS);
    // BIAS folded into the y constant so t = BIAS - |p-y|^2 > 0.
    {
        float y0, y1, y2;
        if (first) {
            int n = nbase + tid;
            y0 = xb[n] * s; y1 = xb[NPTS + n] * s; y2 = xb[2 * NPTS + n] * s;
        } else {
            float4 a = accIn[b * NPTS + nbase + tid];
            float inv = 1.0f / a.w;
            y0 = a.x * inv; y1 = a.y * inv; y2 = a.z * inv;
        }
        ypar[tid] = make_float4(y0, y1, y2,
                                BIASF - fmaf(y0, y0, fmaf(y1, y1, y2 * y2)));
    }
    __syncthreads();

    v2f Yx[4], Yy[4], Yz[4], Yw[4], Ax[4], Ay[4], Az[4], Aw[4];
#pragma unroll
    for (int j = 0; j < 4; ++j) {
        float4 yp = ypar[lane + 64 * j];
        Yx[j] = splat2(yp.x); Yy[j] = splat2(yp.y);
        Yz[j] = splat2(yp.z); Yw[j] = splat2(yp.w);
        Ax[j] = splat2(0.f); Ay[j] = splat2(0.f);
        Az[j] = splat2(0.f); Aw[j] = splat2(0.f);
    }

    const float* xsw = xs + wv * WSLICE;
    const float* ysw = ys + wv * WSLICE;
    const float* zsw = zs + wv * WSLICE;
    const float* wsw = ws + wv * WSLICE;

    const v2f T23 = splat2(T23F);
    const v2f A2  = splat2(A2F);
    const v2f B2  = splat2(B2F);

    // Hot loop: 8 m per iteration as two 4-m sub-blocks.
    for (int i = 0; i < WSLICE; i += 8) {
#pragma unroll
        for (int half = 0; half < 2; ++half) {
            const int o = i + 4 * half;
            float4 PX = *(const float4*)(xsw + o);
            float4 PY = *(const float4*)(ysw + o);
            float4 PZ = *(const float4*)(zsw + o);
            float4 PW = *(const float4*)(wsw + o);
            v2f px0 = (v2f){PX.x, PX.y}, px1 = (v2f){PX.z, PX.w};
            v2f py0 = (v2f){PY.x, PY.y}, py1 = (v2f){PY.z, PY.w};
            v2f pz0 = (v2f){PZ.x, PZ.y}, pz1 = (v2f){PZ.z, PZ.w};
            v2f pw0 = (v2f){PW.x, PW.y}, pw1 = (v2f){PW.z, PW.w};
#pragma unroll
            for (int j = 0; j < 4; ++j) {
                // t = 2p.y - |p|^2 + (BIAS - |y|^2) = BIAS - |p-y|^2
                v2f t0 = pw0 + Yw[j];
                t0 = __builtin_elementwise_fma(pz0, Yz[j], t0);
                t0 = __builtin_elementwise_fma(py0, Yy[j], t0);
                t0 = __builtin_elementwise_fma(px0, Yx[j], t0);
                v2f t1 = pw1 + Yw[j];
                t1 = __builtin_elementwise_fma(pz1, Yz[j], t1);
                t1 = __builtin_elementwise_fma(py1, Yy[j], t1);
                t1 = __builtin_elementwise_fma(px1, Yx[j], t1);
                v2f w0 = fast_exp2(t0, T23, A2, B2);
                v2f w1 = fast_exp2(t1, T23, A2, B2);
                Ax[j] = __builtin_elementwise_fma(w0, px0, Ax[j]);
                Ay[j] = __builtin_elementwise_fma(w0, py0, Ay[j]);
                Az[j] = __builtin_elementwise_fma(w0, pz0, Az[j]);
                Aw[j] += w0;
                Ax[j] = __builtin_elementwise_fma(w1, px1, Ax[j]);
                Ay[j] = __builtin_elementwise_fma(w1, py1, Ay[j]);
                Az[j] = __builtin_elementwise_fma(w1, pz1, Az[j]);
                Aw[j] += w1;
            }
        }
    }

    // Cross-wave reduction (red overlays staging; staging dead now).
    __syncthreads();
#pragma unroll
    for (int j = 0; j < 4; ++j) {
        red[wv * NPB + lane + 64 * j] =
            make_float4(Ax[j].x + Ax[j].y, Ay[j].x + Ay[j].y,
                        Az[j].x + Az[j].y, Aw[j].x + Aw[j].y);
    }
    __syncthreads();
    {
        float4 r0 = red[tid];
        float4 r1 = red[NPB + tid];
        float4 r2 = red[2 * NPB + tid];
        float4 r3 = red[3 * NPB + tid];
        // coords were accumulated with the 2x fold -> scale by 0.5
        float ox = 0.5f * ((r0.x + r1.x) + (r2.x + r3.x));
        float oy = 0.5f * ((r0.y + r1.y) + (r2.y + r3.y));
        float oz = 0.5f * ((r0.z + r1.z) + (r2.z + r3.z));
        float od = (r0.w + r1.w) + (r2.w + r3.w);
        float* dst = (float*)&accOut[b * NPTS + nbase + tid];
        atomicAdd(dst + 0, ox);
        atomicAdd(dst + 1, oy);
        atomicAdd(dst + 2, oz);
        atomicAdd(dst + 3, od);
    }
}

__global__ __launch_bounds__(256) void ms_pack(const float4* __restrict__ acc4,
                                               float* __restrict__ out,
                                               float invs) {
    int gid = blockIdx.x * 256 + threadIdx.x;
    int b = gid / NPTS;
    int n = gid - b * NPTS;
    float4 a = acc4[gid];
    float f = invs / a.w;                       // unscale + normalize
    float* ob = out + b * 3 * NPTS;
    ob[n]            = a.x * f;
    ob[NPTS + n]     = a.y * f;
    ob[2 * NPTS + n] = a.z * f;
}

extern "C" void kernel_launch(void* const* d_in, const int* in_sizes, int n_in,
                              void* d_out, int out_size, void* d_ws, size_t ws_size,
                              hipStream_t stream) {
    const float* x = (const float*)d_in[0];
    float* out = (float*)d_out;
    float s = sqrtf(50.0f * LOG2E);                 // 8.4932...

    float4* acc = (float4*)d_ws;                    // 5 * TOT * 16 B = 1.47 MB
    float* soa = (float*)(acc + (size_t)5 * TOT);   // NB*4*NPTS floats = 295 KB

    // Zero all 5 accumulator buffers (atomic targets) in one async memset.
    hipMemsetAsync(acc, 0, (size_t)5 * TOT * sizeof(float4), stream);

    for (int it = 0; it < 5; ++it) {
        const float4* accIn = (it == 0) ? nullptr : acc + (size_t)(it - 1) * TOT;
        ms_iter<<<GRIDSZ, 256, 0, stream>>>(
            x, soa, accIn, acc + (size_t)it * TOT, s, it == 0 ? 1 : 0);
    }
    ms_pack<<<TOT / 256, 256, 0, stream>>>(acc + (size_t)4 * TOT, out, 1.0f / s);
}

// Round 16
// 234.155 us; speedup vs baseline: 1.2269x; 1.2269x over previous
//
#include <hip/hip_runtime.h>
#include <math.h>

// MeanShift: x (2,3,96,96) fp32, 5 iters of all-pairs Gaussian-weighted mean.
// FINAL (R11 revert — best measured: 232.7us). Closed performance model:
//   busy floor = 390 cyc per 16-pair wave-superiter (128 cyc v_pk_fma_f32 +
//   16 x ~16 cyc v_exp_f32 on the issue port) -> 26.4 us/iter x 5 = 132 us;
//   port utilization ~65% (orchestration-invariant across 8 variants:
//   multi-kernel / fused+barriers / all-resident / SoA staging / prefetch /
//   unroll all within +-2%); + ~4-8 us/dispatch overhead -> ~233 us wall.
// Ruled out: MFMA (K=3 + layout round-trip loses), fast-exp bit tricks
// (R7/R15: no packed floor/cvt on gfx950 -> scalarization, busy 26.5->39us),
// kernel fusion (R10: in-kernel barriers cost more than dispatch boundaries),
// min-waves>4 (R12: VGPR cap < ~90 live regs -> accumulator spills, 5x).
//
// Math: scaled space s = sqrt(50*log2e); w = exp2(2p.y - |p|^2 - |y|^2).
// LDS stages (2px,2py,2pz,-|p|^2); ypar stores PLAIN y (storing 2y was the
// rounds-5/6 NaN bug: u doubled -> cvt saturation -> NaN-as-float).

typedef float v2f __attribute__((ext_vector_type(2)));

#define NPTS   9216            // 96*96
#define NB     2
#define TOT    (NB * NPTS)     // 18432
#define MSPLIT 32              // m-slices per n-tile
#define SLICE  (NPTS / MSPLIT) // 288 m per block
#define WSLICE (SLICE / 4)     // 72 m per wave
#define NPB    256             // n per block (4 per thread)
#define NTILES (NPTS / NPB)    // 36
#define LOG2E  1.44269504088896340736f

__device__ __forceinline__ v2f splat2(float v) { return (v2f){v, v}; }

// acc[t][gid] = float4(num0,num1,num2,den), t=0..4, pre-zeroed, atomic-combined.

__global__ __launch_bounds__(256, 4) void ms_iter(const float* __restrict__ x,
                                                  const float4* __restrict__ accIn,
                                                  float4* __restrict__ accOut,
                                                  float s, int first) {
    __shared__ float4 smem[1024];               // 16 KB
    float* const xs = (float*)smem;             // [SLICE] 2*px
    float* const ys = xs + SLICE;               // 2*py
    float* const zs = ys + SLICE;               // 2*pz
    float* const ws = zs + SLICE;               // -|p|^2
    float4* const ypar = smem + SLICE;          // [NPB] (y0,y1,y2,-|y|^2)
    float4* const red  = smem;                  // [4][NPB] overlay (post-loop)

    const int tid  = threadIdx.x;
    const int lane = tid & 63;
    const int wv   = tid >> 6;
    const int k    = blockIdx.x % MSPLIT;
    const int tile = blockIdx.x / MSPLIT;
    const int b    = tile / NTILES;
    const int nt   = tile - b * NTILES;
    const int nbase = nt * NPB;
    const float* xb = x + b * 3 * NPTS;
    const int mbeg = k * SLICE;

    // SoA staging, scaled, 2x folded into coords.
    for (int i = tid; i < SLICE; i += 256) {
        int g = mbeg + i;
        float px = xb[g] * s;
        float py = xb[NPTS + g] * s;
        float pz = xb[2 * NPTS + g] * s;
        xs[i] = 2.f * px;
        ys[i] = 2.f * py;
        zs[i] = 2.f * pz;
        ws[i] = -fmaf(px, px, fmaf(py, py, pz * pz));
    }
    // y for this iteration (scaled space). PLAIN y (2x lives in LDS).
    {
        float y0, y1, y2;
        if (first) {
            int n = nbase + tid;
            y0 = xb[n] * s; y1 = xb[NPTS + n] * s; y2 = xb[2 * NPTS + n] * s;
        } else {
            float4 a = accIn[b * NPTS + nbase + tid];
            float inv = 1.0f / a.w;
            y0 = a.x * inv; y1 = a.y * inv; y2 = a.z * inv;
        }
        ypar[tid] = make_float4(y0, y1, y2,
                                -fmaf(y0, y0, fmaf(y1, y1, y2 * y2)));
    }
    __syncthreads();

    v2f Yx[4], Yy[4], Yz[4], Yw[4], Ax[4], Ay[4], Az[4], Aw[4];
#pragma unroll
    for (int j = 0; j < 4; ++j) {
        float4 yp = ypar[lane + 64 * j];
        Yx[j] = splat2(yp.x); Yy[j] = splat2(yp.y);
        Yz[j] = splat2(yp.z); Yw[j] = splat2(yp.w);
        Ax[j] = splat2(0.f); Ay[j] = splat2(0.f);
        Az[j] = splat2(0.f); Aw[j] = splat2(0.f);
    }

    const float* xsw = xs + wv * WSLICE;
    const float* ysw = ys + wv * WSLICE;
    const float* zsw = zs + wv * WSLICE;
    const float* wsw = ws + wv * WSLICE;

    // 8 m per loop iteration as two 4-m sub-blocks (9 iterations total).
    for (int i = 0; i < WSLICE; i += 8) {
#pragma unroll
        for (int half = 0; half < 2; ++half) {
            const int o = i + 4 * half;
            float4 PX = *(const float4*)(xsw + o);
            float4 PY = *(const float4*)(ysw + o);
            float4 PZ = *(const float4*)(zsw + o);
            float4 PW = *(const float4*)(wsw + o);
            v2f px0 = (v2f){PX.x, PX.y}, px1 = (v2f){PX.z, PX.w};
            v2f py0 = (v2f){PY.x, PY.y}, py1 = (v2f){PY.z, PY.w};
            v2f pz0 = (v2f){PZ.x, PZ.y}, pz1 = (v2f){PZ.z, PZ.w};
            v2f pw0 = (v2f){PW.x, PW.y}, pw1 = (v2f){PW.z, PW.w};
#pragma unroll
            for (int j = 0; j < 4; ++j) {
                // u = 2p.y - |p|^2 - |y|^2 <= 0
                v2f t0 = pw0 + Yw[j];
                t0 = __builtin_elementwise_fma(pz0, Yz[j], t0);
                t0 = __builtin_elementwise_fma(py0, Yy[j], t0);
                t0 = __builtin_elementwise_fma(px0, Yx[j], t0);
                v2f t1 = pw1 + Yw[j];
                t1 = __builtin_elementwise_fma(pz1, Yz[j], t1);
                t1 = __builtin_elementwise_fma(py1, Yy[j], t1);
                t1 = __builtin_elementwise_fma(px1, Yx[j], t1);
                v2f w0, w1;
                w0.x = __builtin_amdgcn_exp2f(t0.x);
                w0.y = __builtin_amdgcn_exp2f(t0.y);
                w1.x = __builtin_amdgcn_exp2f(t1.x);
                w1.y = __builtin_amdgcn_exp2f(t1.y);
                Ax[j] = __builtin_elementwise_fma(w0, px0, Ax[j]);
                Ay[j] = __builtin_elementwise_fma(w0, py0, Ay[j]);
                Az[j] = __builtin_elementwise_fma(w0, pz0, Az[j]);
                Aw[j] += w0;
                Ax[j] = __builtin_elementwise_fma(w1, px1, Ax[j]);
                Ay[j] = __builtin_elementwise_fma(w1, py1, Ay[j]);
                Az[j] = __builtin_elementwise_fma(w1, pz1, Az[j]);
                Aw[j] += w1;
            }
        }
    }

    // Cross-wave reduction (red overlays staging; staging dead now).
    __syncthreads();
#pragma unroll
    for (int j = 0; j < 4; ++j) {
        red[wv * NPB + lane + 64 * j] =
            make_float4(Ax[j].x + Ax[j].y, Ay[j].x + Ay[j].y,
                        Az[j].x + Az[j].y, Aw[j].x + Aw[j].y);
    }
    __syncthreads();
    {
        float4 r0 = red[tid];
        float4 r1 = red[NPB + tid];
        float4 r2 = red[2 * NPB + tid];
        float4 r3 = red[3 * NPB + tid];
        // coords were accumulated with the 2x fold -> scale by 0.5
        float ox = 0.5f * ((r0.x + r1.x) + (r2.x + r3.x));
        float oy = 0.5f * ((r0.y + r1.y) + (r2.y + r3.y));
        float oz = 0.5f * ((r0.z + r1.z) + (r2.z + r3.z));
        float od = (r0.w + r1.w) + (r2.w + r3.w);
        float* dst = (float*)&accOut[b * NPTS + nbase + tid];
        atomicAdd(dst + 0, ox);
        atomicAdd(dst + 1, oy);
        atomicAdd(dst + 2, oz);
        atomicAdd(dst + 3, od);
    }
}

__global__ __launch_bounds__(256) void ms_pack(const float4* __restrict__ acc4,
                                               float* __restrict__ out,
                                               float invs) {
    int gid = blockIdx.x * 256 + threadIdx.x;
    int b = gid / NPTS;
    int n = gid - b * NPTS;
    float4 a = acc4[gid];
    float f = invs / a.w;                       // unscale + normalize
    float* ob = out + b * 3 * NPTS;
    ob[n]            = a.x * f;
    ob[NPTS + n]     = a.y * f;
    ob[2 * NPTS + n] = a.z * f;
}

extern "C" void kernel_launch(void* const* d_in, const int* in_sizes, int n_in,
                              void* d_out, int out_size, void* d_ws, size_t ws_size,
                              hipStream_t stream) {
    const float* x = (const float*)d_in[0];
    float* out = (float*)d_out;
    float s = sqrtf(50.0f * LOG2E);                 // 8.4932...

    float4* acc = (float4*)d_ws;                    // 5 * TOT * 16 B = 1.47 MB

    // Zero all 5 accumulator buffers (atomic targets) in one async memset.
    hipMemsetAsync(acc, 0, (size_t)5 * TOT * sizeof(float4), stream);

    for (int it = 0; it < 5; ++it) {
        const float4* accIn = (it == 0) ? nullptr : acc + (size_t)(it - 1) * TOT;
        ms_iter<<<NB * NTILES * MSPLIT, 256, 0, stream>>>(
            x, accIn, acc + (size_t)it * TOT, s, it == 0 ? 1 : 0);
    }
    ms_pack<<<TOT / 256, 256, 0, stream>>>(acc + (size_t)4 * TOT, out, 1.0f / s);
}